// Round 1
// baseline (364.094 us; speedup 1.0000x reference)
//
#include <hip/hip_runtime.h>
#include <stdint.h>

#define NGRAPH 512
#define NPG    152
#define NNODES (NGRAPH*NPG)     // 77824
#define DEG    8
#define EPG    (NPG*DEG)        // 1216 edges per graph
#define NEDGE  (NNODES*DEG)     // 622592
#define CCH    192
#define HEADS  6
#define HID    32
#define NSEG   (NPG+EPG)        // 1368 = edges + self loops per graph

typedef __attribute__((ext_vector_type(8))) short short8v;
typedef __attribute__((ext_vector_type(4))) float f32x4;

__device__ __forceinline__ unsigned short f2bf(float f){
  union { float f; uint32_t u; } x; x.f = f;
  uint32_t u = x.u;
  return (unsigned short)((u + 0x7fffu + ((u >> 16) & 1u)) >> 16); // RNE
}
__device__ __forceinline__ float bitsf(uint32_t b){
  union { uint32_t u; float f; } x; x.u = b; return x.f;
}

// ---- W[K][192] f32 -> Wt[192][K] bf16 ----
__global__ void wprep(const float* __restrict__ W, unsigned short* __restrict__ Wt, int K){
  int idx = blockIdx.x*256 + threadIdx.x;
  if (idx < CCH*K){
    int c = idx / K, k = idx - c*K;
    Wt[idx] = f2bf(W[k*CCH + c]);
  }
}

// ---- GEMM: H[M,192] = A[M,K] @ W  (Bt = W^T bf16 [192][K]) ----
template<int K, bool A_BF16>
__global__ __launch_bounds__(256) void gemm_mfma(const void* __restrict__ Ap,
    const unsigned short* __restrict__ Bt, unsigned short* __restrict__ H){
  __shared__ unsigned short lA[64*K];
  __shared__ unsigned short lB[96*K];
  const int t  = threadIdx.x;
  const int m0 = blockIdx.x*64, c0 = blockIdx.y*96;
  const int KC = K/8;

  if (A_BF16){
    const unsigned short* A = (const unsigned short*)Ap;
    for (int i=t; i<64*KC; i+=256){
      int row = i/KC, c8 = i - row*KC;
      int4 v = *(const int4*)(A + (size_t)(m0+row)*K + c8*8);
      *(int4*)((char*)lA + row*(2*K) + ((c8*16) ^ ((row&7)<<4))) = v;
    }
  } else {
    const float* A = (const float*)Ap;
    for (int i=t; i<64*KC; i+=256){
      int row = i/KC, c8 = i - row*KC;
      const float* p = A + (size_t)(m0+row)*K + c8*8;
      float4 v0 = *(const float4*)p;
      float4 v1 = *(const float4*)(p+4);
      short8v pk;
      pk[0]=(short)f2bf(v0.x); pk[1]=(short)f2bf(v0.y); pk[2]=(short)f2bf(v0.z); pk[3]=(short)f2bf(v0.w);
      pk[4]=(short)f2bf(v1.x); pk[5]=(short)f2bf(v1.y); pk[6]=(short)f2bf(v1.z); pk[7]=(short)f2bf(v1.w);
      *(short8v*)((char*)lA + row*(2*K) + ((c8*16) ^ ((row&7)<<4))) = pk;
    }
  }
  for (int i=t; i<96*KC; i+=256){
    int col = i/KC, c8 = i - col*KC;
    int4 v = *(const int4*)(Bt + (size_t)(c0+col)*K + c8*8);
    *(int4*)((char*)lB + col*(2*K) + ((c8*16) ^ ((col&7)<<4))) = v;
  }
  __syncthreads();

  const int wid = t>>6, l = t&63;
  const int wr = wid>>1, wc = wid&1;      // 2x2 wave grid: 32 rows x 48 cols each
  const int r16 = l&15, kq = l>>4;
  f32x4 acc[2][3] = {};
  #pragma unroll
  for (int kk=0; kk<K/32; kk++){
    const int chunk = kk*4 + kq;
    short8v af[2], bf[3];
    #pragma unroll
    for (int m=0;m<2;m++){
      int row = wr*32 + m*16 + r16;
      af[m] = *(const short8v*)((const char*)lA + row*(2*K) + ((chunk*16) ^ ((row&7)<<4)));
    }
    #pragma unroll
    for (int n=0;n<3;n++){
      int col = wc*48 + n*16 + r16;
      bf[n] = *(const short8v*)((const char*)lB + col*(2*K) + ((chunk*16) ^ ((col&7)<<4)));
    }
    #pragma unroll
    for (int m=0;m<2;m++)
      #pragma unroll
      for (int n=0;n<3;n++)
        acc[m][n] = __builtin_amdgcn_mfma_f32_16x16x32_bf16(af[m], bf[n], acc[m][n], 0,0,0);
  }
  const int crow = (l>>4)*4;   // C/D: col = lane&15, row = (lane>>4)*4 + reg  [m89]
  #pragma unroll
  for (int m=0;m<2;m++){
    #pragma unroll
    for (int n=0;n<3;n++){
      int colg = c0 + wc*48 + n*16 + r16;
      #pragma unroll
      for (int r=0;r<4;r++){
        int rowg = m0 + wr*32 + m*16 + crow + r;
        H[(size_t)rowg*CCH + colg] = f2bf(acc[m][n][r]);
      }
    }
  }
}

// ---- fused GAT edge softmax + aggregation + bias + ELU + GraphNorm ----
// one block per (graph, head); 256 threads
template<bool OUT_BF16>
__global__ __launch_bounds__(256) void gat_edge(
    const unsigned short* __restrict__ H,
    const int* __restrict__ esrc, const int* __restrict__ edst,
    const float* __restrict__ a_src, const float* __restrict__ a_dst,
    const float* __restrict__ bias, const float* __restrict__ gw,
    const float* __restrict__ gb, const float* __restrict__ gms,
    void* __restrict__ OUTp)
{
  __shared__ float hN[NPG*HID];          // h for this head, f32
  __shared__ float als[NPG], ald[NPG];
  __shared__ float score[NSEG];
  __shared__ unsigned short ssrc[NSEG];
  __shared__ int epack[EPG];
  __shared__ int cnt[256];               // counts -> inclusive prefix
  __shared__ int woff[NPG];
  __shared__ float ps[8][32];
  __shared__ float mred[32], vred[32];

  const int t    = threadIdx.x;
  const int g    = blockIdx.x & 511;
  const int hd   = blockIdx.x >> 9;
  const int base = g*NPG;

  cnt[t] = (t < NPG) ? 1 : 0;            // self loop pre-counted

  // load h_head (bf16 -> f32), 8 elems per 16B chunk; 608 chunks
  for (int i=t; i<NPG*HID/8; i+=256){
    int n = i>>2, c8 = i&3;
    int4 v = *(const int4*)(H + (size_t)(base+n)*CCH + hd*HID + c8*8);
    uint32_t w0=(uint32_t)v.x, w1=(uint32_t)v.y, w2=(uint32_t)v.z, w3=(uint32_t)v.w;
    float* dst = &hN[n*HID + c8*8];
    float4 lo = { bitsf(w0<<16), bitsf(w0&0xffff0000u), bitsf(w1<<16), bitsf(w1&0xffff0000u) };
    float4 hi = { bitsf(w2<<16), bitsf(w2&0xffff0000u), bitsf(w3<<16), bitsf(w3&0xffff0000u) };
    *(float4*)dst = lo;
    *(float4*)(dst+4) = hi;
  }
  __syncthreads();

  // edge load + count
  for (int i=t; i<EPG; i+=256){
    int s = esrc[g*EPG + i] - base;
    int d = edst[g*EPG + i] - base;
    epack[i] = s | (d<<16);
    atomicAdd(&cnt[d], 1);
  }
  // attention logits: 8 groups of 32 lanes; lane = channel
  const int lane32 = t & 31, grp = t >> 5;
  const float avs = a_src[hd*HID + lane32];
  const float avd = a_dst[hd*HID + lane32];
  #pragma unroll
  for (int k=0;k<19;k++){
    int n = grp + (k<<3);
    float hv = hN[n*HID + lane32];
    float s1 = hv*avs, s2 = hv*avd;
    #pragma unroll
    for (int m=16;m>0;m>>=1){ s1 += __shfl_xor(s1, m, 32); s2 += __shfl_xor(s2, m, 32); }
    if (lane32==0){ als[n]=s1; ald[n]=s2; }
  }
  __syncthreads();

  // inclusive scan of cnt[0..255]
  for (int off=1; off<256; off<<=1){
    int a = cnt[t];
    int b = (t>=off) ? cnt[t-off] : 0;
    __syncthreads();
    cnt[t] = a + b;
    __syncthreads();
  }
  if (t<NPG) woff[t] = (t==0) ? 0 : cnt[t-1];
  __syncthreads();

  // scatter edges into CSR-by-dst with leaky-relu score
  for (int i=t; i<EPG; i+=256){
    int p = epack[i]; int s = p & 0xffff, d = p >> 16;
    float e = als[s] + ald[d];
    e = (e>0.f) ? e : 0.2f*e;
    int pos = atomicAdd(&woff[d], 1);
    score[pos] = e; ssrc[pos] = (unsigned short)s;
  }
  if (t < NPG){
    float e = als[t] + ald[t];
    e = (e>0.f) ? e : 0.2f*e;
    int pos = atomicAdd(&woff[t], 1);
    score[pos] = e; ssrc[pos] = (unsigned short)t;
  }
  __syncthreads();

  // per-dst softmax (serial over in-edges, ~9 avg)
  if (t < NPG){
    int st = (t==0)?0:cnt[t-1], en = cnt[t];
    float m = -1e30f;
    for (int j=st;j<en;j++) m = fmaxf(m, score[j]);
    float sum = 0.f;
    for (int j=st;j<en;j++){ float ex = __expf(score[j]-m); score[j]=ex; sum+=ex; }
    float inv = 1.f/sum;
    for (int j=st;j<en;j++) score[j] *= inv;
  }
  __syncthreads();

  // pull-based aggregation + bias + ELU (kept in registers)
  const float bsv = bias[hd*HID + lane32];
  const float wv  = gw [hd*HID + lane32];
  const float gbv = gb [hd*HID + lane32];
  const float msv = gms[hd*HID + lane32];
  float acc[19];
  #pragma unroll
  for (int k=0;k<19;k++){
    int n = grp + (k<<3);
    int st = (n==0)?0:cnt[n-1], en = cnt[n];
    float a = 0.f;
    for (int j=st;j<en;j++)
      a += score[j] * hN[(int)ssrc[j]*HID + lane32];
    float x = a + bsv;
    acc[k] = (x>0.f) ? x : (__expf(x)-1.f);
  }

  // GraphNorm over the 152 nodes, per channel (this head's 32 channels)
  float psum = 0.f;
  #pragma unroll
  for (int k=0;k<19;k++) psum += acc[k];
  ps[grp][lane32] = psum;
  __syncthreads();
  if (t < 32){
    float s=0.f;
    #pragma unroll
    for (int q=0;q<8;q++) s += ps[q][t];
    mred[t] = s * (1.f/152.f);
  }
  __syncthreads();
  const float mean = mred[lane32];
  float p2 = 0.f;
  #pragma unroll
  for (int k=0;k<19;k++){ acc[k] -= mean*msv; p2 += acc[k]*acc[k]; }
  ps[grp][lane32] = p2;
  __syncthreads();
  if (t < 32){
    float s=0.f;
    #pragma unroll
    for (int q=0;q<8;q++) s += ps[q][t];
    vred[t] = rsqrtf(s*(1.f/152.f) + 1e-5f);
  }
  __syncthreads();
  const float rs = vred[lane32];
  #pragma unroll
  for (int k=0;k<19;k++){
    int n = grp + (k<<3);
    float v = acc[k]*rs*wv + gbv;
    size_t oidx = (size_t)(base+n)*CCH + hd*HID + lane32;
    if (OUT_BF16) ((unsigned short*)OUTp)[oidx] = f2bf(v);
    else          ((float*)OUTp)[oidx] = v;
  }
}

extern "C" void kernel_launch(void* const* d_in, const int* in_sizes, int n_in,
                              void* d_out, int out_size, void* d_ws, size_t ws_size,
                              hipStream_t stream){
  (void)in_sizes; (void)n_in; (void)out_size; (void)ws_size;
  const float* x    = (const float*)d_in[0];
  const int*   ei   = (const int*)  d_in[1];
  const float* W1   = (const float*)d_in[3];
  const float* as1  = (const float*)d_in[4];
  const float* ad1  = (const float*)d_in[5];
  const float* b1   = (const float*)d_in[6];
  const float* W2   = (const float*)d_in[7];
  const float* as2  = (const float*)d_in[8];
  const float* ad2  = (const float*)d_in[9];
  const float* b2   = (const float*)d_in[10];
  const float* gw1  = (const float*)d_in[11];
  const float* gb1  = (const float*)d_in[12];
  const float* gms1 = (const float*)d_in[13];
  const float* gw2  = (const float*)d_in[14];
  const float* gb2  = (const float*)d_in[15];
  const float* gms2 = (const float*)d_in[16];
  const int* esrc = ei;
  const int* edst = ei + NEDGE;

  char* ws = (char*)d_ws;
  unsigned short* Hbuf = (unsigned short*)ws;                               // [N,192] bf16
  unsigned short* Obuf = (unsigned short*)(ws + (size_t)NNODES*CCH*2);      // [N,192] bf16
  unsigned short* Wt1  = (unsigned short*)(ws + (size_t)NNODES*CCH*4);      // [192,128] bf16
  unsigned short* Wt2  = Wt1 + CCH*128;                                     // [192,192] bf16

  wprep<<<(CCH*128+255)/256, 256, 0, stream>>>(W1, Wt1, 128);
  wprep<<<(CCH*192+255)/256, 256, 0, stream>>>(W2, Wt2, 192);

  gemm_mfma<128,false><<<dim3(NNODES/64,2), 256, 0, stream>>>((const void*)x, Wt1, Hbuf);
  gat_edge<true><<<NGRAPH*HEADS, 256, 0, stream>>>(Hbuf, esrc, edst, as1, ad1, b1, gw1, gb1, gms1, (void*)Obuf);
  gemm_mfma<192,true><<<dim3(NNODES/64,2), 256, 0, stream>>>((const void*)Obuf, Wt2, Hbuf);
  gat_edge<false><<<NGRAPH*HEADS, 256, 0, stream>>>(Hbuf, esrc, edst, as2, ad2, b2, gw2, gb2, gms2, d_out);
}